// Round 5
// baseline (259.813 us; speedup 1.0000x reference)
//
#include <hip/hip_runtime.h>
#include <math.h>

#define ALPHA 0.99f
typedef float f4 __attribute__((ext_vector_type(4)));

constexpr int NROWS = 16;
constexpr int NS    = 1 << 21;      // samples per row
constexpr int BT    = 512;          // threads per block
constexpr int R     = 128;          // samples per thread
constexpr int TILE  = BT * R;       // 65536 samples per block
constexpr int BPR   = NS / TILE;    // 32 blocks per row
constexpr int NBLK  = NROWS * BPR;  // 512 blocks  (= 2 per CU, all co-resident)
constexpr int PARK  = 9;            // f4 chunks parked in LDS per thread (72KB/block)
constexpr int KEEP  = 32 - PARK;    // 23 f4 chunks kept in VGPRs (92 regs)

constexpr double dpow(double a, long n){ double r=1.0; while(n>0){ if(n&1) r*=a; a*=a; n>>=1; } return r; }
constexpr double s2c_calc(){ double s=0,p=1; for(int t=1;t<=R;++t){ p*=0.99*0.99; s+=p; } return s; }
constexpr double csum_calc(){ double s=0,pw=1; const double f=dpow(0.99,2L*R); for(int i=0;i<BT;++i){ s+=pw; pw*=f; } return s; }

constexpr float W1  = (float)dpow(0.99, 128);   // scan hop weights alpha^(128*k)
constexpr float W2  = (float)dpow(0.99, 256);
constexpr float W4  = (float)dpow(0.99, 512);
constexpr float W8  = (float)dpow(0.99, 1024);
constexpr float W16 = (float)dpow(0.99, 2048);
constexpr float W32 = (float)dpow(0.99, 4096);
constexpr float ASPAN  = (float)dpow(0.99, 8192);            // wave span (64*128), ~1.6e-36 (normal)
constexpr float S2C    = (float)s2c_calc();
constexpr float CCONST = (float)(s2c_calc()*csum_calc());
constexpr float L2A128 = -1.85594487f;                       // 128*log2(0.99)

// Single fused kernel: phase1 stats (+ park x on-chip), grid barrier, gain, phase2 scale.
__global__ __launch_bounds__(512, 4) void k_fused(const float* __restrict__ x,
                                                  float* __restrict__ stats,
                                                  int* __restrict__ cnt,
                                                  float* __restrict__ out) {
    const int b   = blockIdx.x;
    const int row = b / BPR, jb = b % BPR;
    const int tid = threadIdx.x;
    const int lane = tid & 63, wid = tid >> 6;

    __shared__ f4 park[PARK*BT];            // 73728 B
    __shared__ float waveZ[8], pa[8], pb[8];
    __shared__ float sZb, sgain;

    const size_t base = (size_t)row*NS + (size_t)jb*TILE + (size_t)tid*R;
    const f4* xv = reinterpret_cast<const f4*>(x + base);

    const bool rowstart = (jb==0) && (tid==0);
    float xm1 = rowstart ? 0.0f : x[base-1];

    float z=0.f, p=1.f, S0=0.f, S1=0.f;
    float mprev = ALPHA*xm1;
    f4 keep[KEEP];

#define STEP(xx, FIRST) { float m_ = ALPHA*(xx); float b_ = (FIRST) ? (xx) : (m_-mprev); \
    z = fmaf(ALPHA, z, b_); p *= ALPHA; S0 = fmaf(z,z,S0); S1 = fmaf(z,p,S1); mprev = m_; }

    // ---- phase 1: stream 128 samples, filter (zero-state), park/keep raw x ----
#pragma unroll
    for (int c=0;c<PARK;++c){
        f4 v = xv[c];
        STEP(v.x, rowstart && c==0) STEP(v.y,false) STEP(v.z,false) STEP(v.w,false)
        park[c*BT+tid] = v;
    }
#pragma unroll
    for (int c=PARK;c<32;++c){
        f4 v = xv[c];
        STEP(v.x,false) STEP(v.y,false) STEP(v.z,false) STEP(v.w,false)
        keep[c-PARK] = v;
    }
#undef STEP

    // ---- weighted inclusive scan of thread carries z (hop weight alpha^128) ----
    float incl = z;
    { float t1=__shfl_up(incl,1);  if(lane>=1)  incl=fmaf(W1 ,t1,incl); }
    { float t1=__shfl_up(incl,2);  if(lane>=2)  incl=fmaf(W2 ,t1,incl); }
    { float t1=__shfl_up(incl,4);  if(lane>=4)  incl=fmaf(W4 ,t1,incl); }
    { float t1=__shfl_up(incl,8);  if(lane>=8)  incl=fmaf(W8 ,t1,incl); }
    { float t1=__shfl_up(incl,16); if(lane>=16) incl=fmaf(W16,t1,incl); }
    { float t1=__shfl_up(incl,32); if(lane>=32) incl=fmaf(W32,t1,incl); }

    if (lane==63) waveZ[wid]=incl;
    __syncthreads();

    float P=0.f;
    for (int u=0;u<wid;++u) P=fmaf(ASPAN,P,waveZ[u]);   // state entering this wave

    float excl=__shfl_up(incl,1); if(lane==0) excl=0.f;
    float wl = exp2f((float)lane * L2A128);             // alpha^(128*lane)
    float E  = fmaf(wl,P,excl);                         // state entering this thread

    // per-thread contribution, quadratic in block-incoming state Y
    float ai = fmaf(S2C*E,E, fmaf(2.0f*S1,E,S0));
    float Qi = exp2f((float)tid * L2A128);              // alpha^(128*tid), underflows->0 ok
    float bi = 2.0f*Qi*fmaf(S2C,E,S1);

    if (tid==BT-1) sZb = fmaf(ASPAN,P,incl);            // block zero-state output

    for (int d=32; d; d>>=1){ ai+=__shfl_xor(ai,d); bi+=__shfl_xor(bi,d); }
    if (lane==0){ pa[wid]=ai; pb[wid]=bi; }
    __syncthreads();

    // ---- publish stats + grid barrier (all 512 blocks co-resident by construction) ----
    if (tid==0){
        float A=0.f,B=0.f;
#pragma unroll
        for(int u=0;u<8;++u){ A+=pa[u]; B+=pb[u]; }
        __hip_atomic_store(&stats[b*3+0], A,   __ATOMIC_RELAXED, __HIP_MEMORY_SCOPE_AGENT);
        __hip_atomic_store(&stats[b*3+1], B,   __ATOMIC_RELAXED, __HIP_MEMORY_SCOPE_AGENT);
        __hip_atomic_store(&stats[b*3+2], sZb, __ATOMIC_RELAXED, __HIP_MEMORY_SCOPE_AGENT);
        __threadfence();
        atomicAdd(cnt, 1);
        while (__hip_atomic_load(cnt, __ATOMIC_ACQUIRE, __HIP_MEMORY_SCOPE_AGENT) < NBLK)
            __builtin_amdgcn_s_sleep(8);
    }
    __syncthreads();

    // ---- row gain (wave 0; deterministic tree reduce over 32 block-stats) ----
    if (tid < 64){
        int j = lane & 31;
        const float* st = &stats[((size_t)row*BPR + j)*3];
        float a2 = __hip_atomic_load(&st[0], __ATOMIC_RELAXED, __HIP_MEMORY_SCOPE_AGENT);
        float b2 = __hip_atomic_load(&st[1], __ATOMIC_RELAXED, __HIP_MEMORY_SCOPE_AGENT);
        float zl = __hip_atomic_load(&st[2], __ATOMIC_RELAXED, __HIP_MEMORY_SCOPE_AGENT);
        float zp = __shfl_up(zl,1); if(j==0) zp=0.f;    // Y_in(block j) = Z_{j-1}
        float contrib = fmaf(CCONST, zp*zp, fmaf(b2,zp,a2));
        float s = (lane<32)? contrib : 0.f;
        for (int d=32; d; d>>=1) s += __shfl_xor(s,d);
        if (tid==0){
            float ms   = s * (1.0f/(float)NS);
            float lufs = -0.691f + 10.0f*log10f(ms + 1e-8f);
            float gdb  = fminf(fmaxf(-23.0f-lufs,-30.0f),30.0f);
            sgain = exp2f(gdb*0.1660964047f);           // 10^(gdb/20)
        }
    }
    __syncthreads();
    const float g = sgain;

    // ---- phase 2: scale on-chip data, write out (no x re-read) ----
    f4* ov = reinterpret_cast<f4*>(out + base);
#pragma unroll
    for (int c=0;c<PARK;++c){ f4 v = park[c*BT+tid]; ov[c] = v*g; }
#pragma unroll
    for (int c=0;c<KEEP;++c){ ov[PARK+c] = keep[c]*g; }
}

extern "C" void kernel_launch(void* const* d_in, const int* in_sizes, int n_in,
                              void* d_out, int out_size, void* d_ws, size_t ws_size,
                              hipStream_t stream) {
    const float* x = (const float*)d_in[0];
    float* out   = (float*)d_out;
    int*   cnt   = (int*)d_ws;                 // barrier counter (zeroed below each call)
    float* stats = (float*)d_ws + 16;          // 512 * 3 floats, at byte offset 64

    hipMemsetAsync(d_ws, 0, 64, stream);       // reset barrier (capture-safe)
    k_fused<<<NBLK, BT, 0, stream>>>(x, stats, cnt, out);
}